// Round 8
// baseline (387.916 us; speedup 1.0000x reference)
//
#include <hip/hip_runtime.h>
#include <climits>

typedef __attribute__((ext_vector_type(8))) short s8;      // 8 bf16 = 4 VGPRs
typedef __attribute__((ext_vector_type(4))) float f32x4;   // MFMA acc

#define BQ    256
#define DDIM  256
#define NBANK 100000
#define BN    64                          // bank cols per block (4 col-tiles of 16)
#define NJB   1563                        // ceil(NBANK/BN)
#define INIT64 0xFFFFFFFFFFFFFFFFULL

__device__ inline void splitElem(float x, s8& h, s8& l, int i) {
    unsigned u  = __float_as_uint(x);
    unsigned uh = (u + 0x8000u) & 0xFFFF0000u;
    h[i] = (short)(uh >> 16);
    float lf = x - __uint_as_float(uh);            // exact
    l[i] = (short)((__float_as_uint(lf) + 0x8000u) >> 16);
}

__device__ inline void split8(const float4 v0, const float4 v1, s8& h, s8& l) {
    splitElem(v0.x, h, l, 0); splitElem(v0.y, h, l, 1);
    splitElem(v0.z, h, l, 2); splitElem(v0.w, h, l, 3);
    splitElem(v1.x, h, l, 4); splitElem(v1.y, h, l, 5);
    splitElem(v1.z, h, l, 6); splitElem(v1.w, h, l, 7);
}

__device__ inline float sq8(const float4 v0, const float4 v1, float s) {
    s = fmaf(v0.x, v0.x, s); s = fmaf(v0.y, v0.y, s);
    s = fmaf(v0.z, v0.z, s); s = fmaf(v0.w, v0.w, s);
    s = fmaf(v1.x, v1.x, s); s = fmaf(v1.y, v1.y, s);
    s = fmaf(v1.z, v1.z, s); s = fmaf(v1.w, v1.w, s);
    return s;
}

// Monotone fp32->u32, packed with index: u64 min == (min val, then min idx). Exact.
__device__ inline unsigned long long packMin(float v, int idx) {
    unsigned b = __float_as_uint(v);
    unsigned u = (b & 0x80000000u) ? ~b : (b | 0x80000000u);
    return ((unsigned long long)u << 32) | (unsigned)idx;
}

__device__ inline unsigned long long shflxor64(unsigned long long x, int m) {
    unsigned lo = (unsigned)x, hi = (unsigned)(x >> 32);
    lo = __shfl_xor(lo, m); hi = __shfl_xor(hi, m);
    return ((unsigned long long)hi << 32) | lo;
}

// Kernel P1: split the whole bank into row-major bf16 hi/lo + per-row ||b||^2.
// Pure streaming pass: coalesced 32B reads, coalesced 16B writes. 3125 blocks.
__global__ __launch_bounds__(256) void split_bank(
    const float* __restrict__ bank, s8* __restrict__ bH, s8* __restrict__ bL,
    float* __restrict__ b2)
{
    const int r0  = blockIdx.x * 32;
    const int sub = threadIdx.x >> 5;      // row within pass (0..7)
    const int oct = threadIdx.x & 31;      // k-octet (8 floats)
    #pragma unroll
    for (int p = 0; p < 4; ++p) {
        const int row = r0 + p * 8 + sub;            // 3125*32 == 100000 exactly
        const float* gp = bank + (size_t)row * DDIM + oct * 8;
        const float4 v0 = *(const float4*)gp;
        const float4 v1 = *(const float4*)(gp + 4);
        s8 h, l;
        split8(v0, v1, h, l);
        bH[(size_t)row * 32 + oct] = h;
        bL[(size_t)row * 32 + oct] = l;
        float sq = sq8(v0, v1, 0.f);
        sq += __shfl_xor(sq, 1);           // 32 octet-threads are consecutive lanes
        sq += __shfl_xor(sq, 2);
        sq += __shfl_xor(sq, 4);
        sq += __shfl_xor(sq, 8);
        sq += __shfl_xor(sq, 16);
        if (oct == 0) b2[row] = sq;
    }
}

// Kernel P2: blocks 0-15 split A into MFMA-A-fragment order (RT 0..15, slice 0..7);
// block 16 inits the 512 atomic argmin slots.
__global__ __launch_bounds__(512) void prep(
    const float* __restrict__ feature, s8* __restrict__ fH, s8* __restrict__ fL,
    unsigned long long* __restrict__ slots)
{
    if (blockIdx.x == 16) { slots[threadIdx.x] = INIT64; return; }
    const int t    = blockIdx.x * 512 + threadIdx.x;   // 0..8191
    const int lane = t & 63, ks = (t >> 6) & 7, rt = t >> 9;
    const int row  = rt * 16 + (lane & 15);
    const int k0   = ks * 32 + (lane >> 4) * 8;
    const float* p = feature + (size_t)row * DDIM + k0;
    const float4 v0 = *(const float4*)p;
    const float4 v1 = *(const float4*)(p + 4);
    s8 h, l;
    split8(v0, v1, h, l);
    fH[t] = h; fL[t] = l;
}

// Kernel G: pure load->MFMA GEMM + fused masked argmin (packed atomicMin slots).
// 512 thr = 8 waves; wave w owns rows w*32..+31 (2 row-tiles), all 4 col-tiles.
// B frags are direct 16B loads of PRE-SPLIT bf16 (no VALU between load and MFMA);
// A frags pre-split fragment-ordered (L2-hot). No LDS tiles, no main-loop barriers.
__global__ __launch_bounds__(512, 2) void gemm_argmin(
    const s8* __restrict__ fH, const s8* __restrict__ fL,
    const s8* __restrict__ bH, const s8* __restrict__ bL,
    const float* __restrict__ b2,
    const int* __restrict__ cluster_label, const int* __restrict__ class_label,
    const int* __restrict__ cluster_idx,  const int* __restrict__ gt_label,
    unsigned long long* __restrict__ slots)
{
    __shared__ int rowGt[BQ], rowClu[BQ];
    const int tid = threadIdx.x;
    const int jb  = blockIdx.x;
    const int j0  = jb * BN;

    if (tid < BQ) { rowGt[tid] = gt_label[tid]; rowClu[tid] = cluster_idx[tid]; }
    __syncthreads();                       // the only barrier

    const int w = tid >> 6, lane = tid & 63;
    const int g = lane >> 4, c = lane & 15;

    // Per-lane column state (col = j0 + ct*16 + c, clamped; OOB masked in epilogue)
    int clsR[4], cluR[4];
    float b2r[4];
    const s8* pHc[4];
    const s8* pLc[4];
    #pragma unroll
    for (int ct = 0; ct < 4; ++ct) {
        const int jc = min(j0 + ct * 16 + c, NBANK - 1);
        clsR[ct] = class_label[jc];
        cluR[ct] = cluster_label[jc];
        b2r[ct]  = b2[jc];
        pHc[ct]  = bH + (size_t)jc * 32 + g;   // + s*4 per slice
        pLc[ct]  = bL + (size_t)jc * 32 + g;
    }

    f32x4 acc[4][2];
    #pragma unroll
    for (int ct = 0; ct < 4; ++ct) { acc[ct][0] = (f32x4){0,0,0,0}; acc[ct][1] = (f32x4){0,0,0,0}; }

    #pragma unroll
    for (int s = 0; s < 8; ++s) {
        s8 bh[4], bl[4], aH[2], aL[2];
        #pragma unroll
        for (int ct = 0; ct < 4; ++ct) {
            bh[ct] = pHc[ct][s * 4];
            bl[ct] = pLc[ct][s * 4];
        }
        #pragma unroll
        for (int rt = 0; rt < 2; ++rt) {
            aH[rt] = fH[((w * 2 + rt) * 8 + s) * 64 + lane];
            aL[rt] = fL[((w * 2 + rt) * 8 + s) * 64 + lane];
        }
        #pragma unroll
        for (int ct = 0; ct < 4; ++ct)
            #pragma unroll
            for (int rt = 0; rt < 2; ++rt) {
                acc[ct][rt] = __builtin_amdgcn_mfma_f32_16x16x32_bf16(aH[rt], bh[ct], acc[ct][rt], 0, 0, 0);
                acc[ct][rt] = __builtin_amdgcn_mfma_f32_16x16x32_bf16(aH[rt], bl[ct], acc[ct][rt], 0, 0, 0);
                acc[ct][rt] = __builtin_amdgcn_mfma_f32_16x16x32_bf16(aL[rt], bh[ct], acc[ct][rt], 0, 0, 0);
                acc[ct][rt] = __builtin_amdgcn_mfma_f32_16x16x32_bf16(aL[rt], bl[ct], acc[ct][rt], 0, 0, 0);
            }
    }

    // Epilogue: C/D layout col=lane&15, row=g*4+reg (HW-verified, absmax 0 R3-R7)
    #pragma unroll
    for (int rt = 0; rt < 2; ++rt) {
        #pragma unroll
        for (int r = 0; r < 4; ++r) {
            const int row  = w * 32 + rt * 16 + g * 4 + r;
            const int myGt = rowGt[row], myClu = rowClu[row];
            unsigned long long pkP = INIT64, pkD = INIT64;
            #pragma unroll
            for (int ct = 0; ct < 4; ++ct) {
                const int jg = j0 + ct * 16 + c;
                const float sc = fmaf(-2.f, acc[ct][rt][r], b2r[ct]);
                if (jg < NBANK && clsR[ct] != myGt) {
                    const unsigned long long pk = packMin(sc, jg);
                    if (pk < pkD) pkD = pk;
                    if (cluR[ct] == myClu && pk < pkP) pkP = pk;
                }
            }
            #pragma unroll
            for (int off = 1; off < 16; off <<= 1) {   // 16-lane group shares this row
                unsigned long long t0 = shflxor64(pkP, off);
                if (t0 < pkP) pkP = t0;
                t0 = shflxor64(pkD, off);
                if (t0 < pkD) pkD = t0;
            }
            if (c == 0) {
                if (pkP != INIT64) {
                    unsigned long long cur = *(const volatile unsigned long long*)(slots + row);
                    if (pkP < cur) atomicMin(slots + row, pkP);
                }
                if (pkD != INIT64) {
                    unsigned long long cur = *(const volatile unsigned long long*)(slots + 256 + row);
                    if (pkD < cur) atomicMin(slots + 256 + row, pkD);
                }
            }
        }
    }
}

// Kernel 2: decode slots (primary else fallback), gather bank row.
__global__ __launch_bounds__(256) void gather(
    const unsigned long long* __restrict__ slots,
    const float* __restrict__ bank, float* __restrict__ out)
{
    const int row = blockIdx.x, t = threadIdx.x;
    __shared__ int sIdx;
    if (t == 0) {
        unsigned long long p = slots[row];
        unsigned long long d = slots[256 + row];
        unsigned long long chosen = (p != INIT64) ? p : d;
        sIdx = (chosen != INIT64) ? (int)(unsigned)(chosen & 0xFFFFFFFFu) : 0;
    }
    __syncthreads();
    out[row * DDIM + t] = bank[(size_t)sIdx * DDIM + t];
}

extern "C" void kernel_launch(void* const* d_in, const int* in_sizes, int n_in,
                              void* d_out, int out_size, void* d_ws, size_t ws_size,
                              hipStream_t stream) {
    const float* feature       = (const float*)d_in[0];
    const float* bank          = (const float*)d_in[1];
    const int*   cluster_label = (const int*)d_in[2];
    const int*   class_label   = (const int*)d_in[3];
    const int*   cluster_idx   = (const int*)d_in[4];
    const int*   gt_label      = (const int*)d_in[5];
    float* out = (float*)d_out;

    // Workspace layout (16B aligned):
    //   bH: NBANK*32 s8 = 51.2 MB   bL: 51.2 MB
    //   fH/fL: 8192 s8 each (128 KB x2)   b2: 400 KB   slots: 4 KB
    s8* bH = (s8*)d_ws;
    s8* bL = bH + (size_t)NBANK * 32;
    s8* fH = bL + (size_t)NBANK * 32;
    s8* fL = fH + 8192;
    float* b2 = (float*)(fL + 8192);
    unsigned long long* slots = (unsigned long long*)(b2 + NBANK);

    hipLaunchKernelGGL(prep, dim3(17), dim3(512), 0, stream, feature, fH, fL, slots);
    hipLaunchKernelGGL(split_bank, dim3(3125), dim3(256), 0, stream, bank, bH, bL, b2);
    hipLaunchKernelGGL(gemm_argmin, dim3(NJB), dim3(512), 0, stream,
                       fH, fL, bH, bL, b2,
                       cluster_label, class_label, cluster_idx, gt_label, slots);
    hipLaunchKernelGGL(gather, dim3(BQ), dim3(256), 0, stream, slots, bank, out);
}